// Round 8
// baseline (115.618 us; speedup 1.0000x reference)
//
#include <hip/hip_runtime.h>
#include <stdint.h>
#include <stddef.h>

#define DIM 1024
#define NEXP 8
#define HID 512
#define NTOK 16384  // 4 * 4096
#define NB_HIST 64  // histogram/scatter blocks (256 tokens each)
#define NB_ROUTER 1024  // router blocks (16 tokens each)
#define NB_CAST 512     // cast blocks prepended to the router grid

typedef __attribute__((ext_vector_type(4))) float f32x4;
typedef __attribute__((ext_vector_type(8))) short short8;
typedef __attribute__((ext_vector_type(4))) unsigned short u16x4;
typedef __attribute__((ext_vector_type(8))) unsigned short u16x8;

__device__ __forceinline__ unsigned short f2b(float f) {
  unsigned int u = __float_as_uint(f);
  return (unsigned short)((u + 0x7FFFu + ((u >> 16) & 1u)) >> 16);  // RNE
}

// 16B async global->LDS. lds ptr must be wave-uniform; HW writes base + lane*16.
__device__ __forceinline__ void gload_lds16(const unsigned short* g, unsigned short* l) {
  __builtin_amdgcn_global_load_lds((const __attribute__((address_space(1))) void*)g,
                                   (__attribute__((address_space(3))) void*)l, 16, 0, 0);
}

// Fused cast + router.
// Blocks [0, NB_CAST): grid-stride fp32->bf16 weight cast (runs early so the
// GEMM weights stream out while router blocks grind).
// Blocks [NB_CAST, NB_CAST+NB_ROUTER): router, 4 waves x 4 tokens/wave.
// Round-8 router structure: phase A issues ALL 16 x-loads back-to-back into
// registers (16 outstanding loads/wave -> MLP; rounds 6-7 showed the compiler
// interleaved load->convert->store chains, serializing on vmcnt), phase B
// converts + stores 16B u16x8 (lane owns 8 contiguous floats), phase C runs
// the wr-dot from resident registers.
__global__ __launch_bounds__(256) void k_router_cast(
    const float* __restrict__ x, const float* __restrict__ wr,
    int* __restrict__ eid, unsigned short* __restrict__ xb,
    const float* __restrict__ wfc, const float* __restrict__ wpj,
    unsigned short* __restrict__ oa, unsigned short* __restrict__ ob) {
  int bid = blockIdx.x;
  if (bid >= NB_CAST) {
    int w = threadIdx.x >> 6, lane = threadIdx.x & 63;
    int t0 = (bid - NB_CAST) * 16 + w * 4;  // 4 tokens per wave
    const float* xr = x + (size_t)t0 * DIM;
    unsigned short* xbr = xb + (size_t)t0 * DIM;

    // phase A: all 16 x-loads in flight (lane covers 8 contiguous floats per i)
    f32x4 xv[4][2][2];
#pragma unroll
    for (int j = 0; j < 4; j++)
#pragma unroll
      for (int i = 0; i < 2; i++) {
        xv[j][i][0] = *(const f32x4*)(xr + j * DIM + lane * 8 + 512 * i);
        xv[j][i][1] = *(const f32x4*)(xr + j * DIM + lane * 8 + 512 * i + 4);
      }

    // phase B: convert + 16B stores
#pragma unroll
    for (int j = 0; j < 4; j++)
#pragma unroll
      for (int i = 0; i < 2; i++) {
        u16x8 u;
        u[0] = f2b(xv[j][i][0].x); u[1] = f2b(xv[j][i][0].y);
        u[2] = f2b(xv[j][i][0].z); u[3] = f2b(xv[j][i][0].w);
        u[4] = f2b(xv[j][i][1].x); u[5] = f2b(xv[j][i][1].y);
        u[6] = f2b(xv[j][i][1].z); u[7] = f2b(xv[j][i][1].w);
        *(u16x8*)(xbr + j * DIM + lane * 8 + 512 * i) = u;
      }

    // phase C: router dots from resident registers
    float s[4][NEXP];
#pragma unroll
    for (int j = 0; j < 4; j++)
#pragma unroll
      for (int e = 0; e < NEXP; e++) s[j][e] = 0.f;
#pragma unroll
    for (int i = 0; i < 2; i++)
#pragma unroll
      for (int e = 0; e < NEXP; e++) {
        f32x4 wlo = *(const f32x4*)(wr + e * DIM + lane * 8 + 512 * i);
        f32x4 whi = *(const f32x4*)(wr + e * DIM + lane * 8 + 512 * i + 4);
#pragma unroll
        for (int j = 0; j < 4; j++) {
          s[j][e] += xv[j][i][0].x * wlo.x + xv[j][i][0].y * wlo.y +
                     xv[j][i][0].z * wlo.z + xv[j][i][0].w * wlo.w;
          s[j][e] += xv[j][i][1].x * whi.x + xv[j][i][1].y * whi.y +
                     xv[j][i][1].z * whi.z + xv[j][i][1].w * whi.w;
        }
      }
#pragma unroll
    for (int j = 0; j < 4; j++)
#pragma unroll
      for (int e = 0; e < NEXP; e++) {
        float v = s[j][e];
#pragma unroll
        for (int off = 32; off > 0; off >>= 1) v += __shfl_xor(v, off);
        s[j][e] = v;
      }
    if (lane == 0) {
#pragma unroll
      for (int j = 0; j < 4; j++) {
        int be = 0;
        float bv = s[j][0];
#pragma unroll
        for (int e = 1; e < NEXP; e++) {
          if (s[j][e] > bv) { bv = s[j][e]; be = e; }
        }
        eid[t0 + j] = be;
      }
    }
  } else {
    const int n4 = NEXP * HID * DIM / 4;
    int stride = NB_CAST * 256;
    for (int i = bid * 256 + (int)threadIdx.x; i < n4; i += stride) {
      f32x4 va = ((const f32x4*)wfc)[i];
      f32x4 vb = ((const f32x4*)wpj)[i];
      u16x4 ua, ub;
      ua.x = f2b(va.x); ua.y = f2b(va.y); ua.z = f2b(va.z); ua.w = f2b(va.w);
      ub.x = f2b(vb.x); ub.y = f2b(vb.y); ub.z = f2b(vb.z); ub.w = f2b(vb.w);
      ((u16x4*)oa)[i] = ua;
      ((u16x4*)ob)[i] = ub;
    }
  }
}

__global__ __launch_bounds__(256) void k_hist(const int* __restrict__ eid,
                                              int* __restrict__ bc) {
  __shared__ int h[NEXP];
  if (threadIdx.x < NEXP) h[threadIdx.x] = 0;
  __syncthreads();
  int tok = blockIdx.x * (NTOK / NB_HIST) + threadIdx.x;
  atomicAdd(&h[eid[tok]], 1);
  __syncthreads();
  if (threadIdx.x < NEXP) bc[blockIdx.x * NEXP + threadIdx.x] = h[threadIdx.x];
}

__global__ void k_scan(const int* __restrict__ bc, int* __restrict__ offs,
                       int* __restrict__ base) {
  __shared__ int cnt[NEXP];
  __shared__ int so[NEXP + 1];
  int t = threadIdx.x;
  if (t < NEXP) {
    int run = 0;
    for (int b = 0; b < NB_HIST; b++) {
      base[b * NEXP + t] = run;
      run += bc[b * NEXP + t];
    }
    cnt[t] = run;
  }
  __syncthreads();
  if (t == 0) {
    int a = 0;
    for (int e = 0; e < NEXP; e++) { so[e] = a; a += cnt[e]; }
    so[NEXP] = a;
  }
  __syncthreads();
  if (t < NEXP + 1) offs[t] = so[t];
  for (int i = t; i < NB_HIST * NEXP; i += blockDim.x) base[i] += so[i % NEXP];
}

__global__ __launch_bounds__(256) void k_scatter(const int* __restrict__ eid,
                                                 const int* __restrict__ base,
                                                 int* __restrict__ tlist) {
  __shared__ int cur[NEXP];
  if (threadIdx.x < NEXP) cur[threadIdx.x] = base[blockIdx.x * NEXP + threadIdx.x];
  __syncthreads();
  int tok = blockIdx.x * (NTOK / NB_HIST) + threadIdx.x;
  int e = eid[tok];
  int pos = atomicAdd(&cur[e], 1);
  tlist[pos] = tok;
}

// Grouped GEMM, C[m,n] = sum_k A[m,k]*B[n,k], bf16, K-contiguous.
// BK=32, ring-3 LDS (48 KB -> 3 blocks/CU), depth-2 global_load_lds prefetch,
// one barrier/step, counted vmcnt(4). XOR swizzle chunk ^= row&3 (2-way = free).
// XCD-chunked 1-D grid, (expert, m-block, n-block) with n fastest.
template <int KDIM, int NDIM, int NB, bool IS_FC>
__global__ __launch_bounds__(256) void k_gemm(
    const unsigned short* __restrict__ xb, const unsigned short* __restrict__ hin,
    const unsigned short* __restrict__ wb, const int* __restrict__ offs,
    const int* __restrict__ tlist, unsigned short* __restrict__ hout,
    float* __restrict__ out) {
  int l = ((int)blockIdx.x & 7) * ((int)gridDim.x >> 3) + ((int)blockIdx.x >> 3);
  int e = -1, mb = 0, nb = 0, acc2 = 0;
#pragma unroll
  for (int i = 0; i < NEXP; i++) {
    int mi = offs[i + 1] - offs[i];
    int tb = ((mi + 127) >> 7) * NB;
    if (e < 0 && l < acc2 + tb) {
      int r = l - acc2;
      e = i; mb = r / NB; nb = r % NB;
    }
    acc2 += tb;
  }
  if (e < 0) return;
  int off = offs[e];
  int me = offs[e + 1] - off;
  int m0 = mb * 128;
  int n0 = nb * 128;

  __shared__ unsigned short lds[3][2][128 * 32];  // 48 KB ring-3

  int t = threadIdx.x;
  int lane = t & 63, w = t >> 6;
  int wm = w >> 1, wn = w & 1;  // 2x2 waves, 64x64 each

  int kb = (lane & 3) ^ ((lane >> 2) & 3);

  const unsigned short* asrc[2];
  const unsigned short* bsrc[2];
#pragma unroll
  for (int i = 0; i < 2; i++) {
    int r = i * 64 + w * 16 + (lane >> 2);
    int gm = m0 + r;
    if (gm > me - 1) gm = me - 1;  // clamp pad rows (masked at epilogue)
    if (IS_FC) {
      int tok = tlist[off + gm];
      asrc[i] = xb + (size_t)tok * KDIM + kb * 8;
    } else {
      asrc[i] = hin + (size_t)(off + gm) * KDIM + kb * 8;
    }
    bsrc[i] = wb + ((size_t)e * NDIM + n0 + r) * (size_t)KDIM + kb * 8;
  }

  f32x4 acc[4][4] = {};
  const int NT = KDIM / 32;

  unsigned short* b0a = &lds[0][0][0]; unsigned short* b0b = &lds[0][1][0];
  unsigned short* b1a = &lds[1][0][0]; unsigned short* b1b = &lds[1][1][0];
  unsigned short* b2a = &lds[2][0][0]; unsigned short* b2b = &lds[2][1][0];

#define STAGE(kt_, da_, db_)                                   \
  do {                                                         \
    gload_lds16(asrc[0] + (kt_) * 32, (da_) + (w * 16) * 32);  \
    gload_lds16(asrc[1] + (kt_) * 32, (da_) + (64 + w * 16) * 32); \
    gload_lds16(bsrc[0] + (kt_) * 32, (db_) + (w * 16) * 32);  \
    gload_lds16(bsrc[1] + (kt_) * 32, (db_) + (64 + w * 16) * 32); \
  } while (0)

  STAGE(0, b0a, b0b);
  STAGE(1, b1a, b1b);

  for (int kt = 0; kt < NT; kt++) {
    if (kt < NT - 1) {
      asm volatile("s_waitcnt vmcnt(4)" ::: "memory");
    } else {
      asm volatile("s_waitcnt vmcnt(0)" ::: "memory");
    }
    __builtin_amdgcn_s_barrier();

    if (kt + 2 < NT) STAGE(kt + 2, b2a, b2b);

    short8 af[4], bf[4];
#pragma unroll
    for (int i = 0; i < 4; i++) {
      int ra = wm * 64 + i * 16 + (lane & 15);
      int ca = (lane >> 4) ^ (ra & 3);
      af[i] = *(const short8*)&b0a[ra * 32 + ca * 8];
      int rb = wn * 64 + i * 16 + (lane & 15);
      int cb = (lane >> 4) ^ (rb & 3);
      bf[i] = *(const short8*)&b0b[rb * 32 + cb * 8];
    }
    __builtin_amdgcn_s_setprio(1);
#pragma unroll
    for (int mi = 0; mi < 4; mi++)
#pragma unroll
      for (int ni = 0; ni < 4; ni++)
        acc[mi][ni] =
            __builtin_amdgcn_mfma_f32_16x16x32_bf16(af[mi], bf[ni], acc[mi][ni], 0, 0, 0);
    __builtin_amdgcn_s_setprio(0);

    unsigned short* ta = b0a; b0a = b1a; b1a = b2a; b2a = ta;
    unsigned short* tb = b0b; b0b = b1b; b1b = b2b; b2b = tb;
  }
#undef STAGE

  // C/D layout: col = lane&15, row = (lane>>4)*4 + reg
  int rb = (lane >> 4) * 4, cb = lane & 15;
#pragma unroll
  for (int mi = 0; mi < 4; mi++) {
#pragma unroll
    for (int j = 0; j < 4; j++) {
      int ml = wm * 64 + mi * 16 + rb + j;
      if (m0 + ml < me) {
        if (IS_FC) {
#pragma unroll
          for (int ni = 0; ni < 4; ni++) {
            int col = n0 + wn * 64 + ni * 16 + cb;
            float v = acc[mi][ni][j];
            v = (v >= 0.f) ? v * v : 0.25f * v * v;  // leaky(0.5) then square
            hout[(size_t)(off + m0 + ml) * HID + col] = f2b(v);
          }
        } else {
          int tok = tlist[off + m0 + ml];
#pragma unroll
          for (int ni = 0; ni < 4; ni++) {
            int col = n0 + wn * 64 + ni * 16 + cb;
            out[(size_t)tok * DIM + col] = acc[mi][ni][j];
          }
        }
      }
    }
  }
}

extern "C" void kernel_launch(void* const* d_in, const int* in_sizes, int n_in,
                              void* d_out, int out_size, void* d_ws, size_t ws_size,
                              hipStream_t stream) {
  const float* x = (const float*)d_in[0];
  const float* wr = (const float*)d_in[1];
  const float* wfc = (const float*)d_in[2];
  const float* wpj = (const float*)d_in[3];
  float* out = (float*)d_out;

  uintptr_t p = (uintptr_t)d_ws;
  int* offs = (int*)p;  p += 256;
  int* bc = (int*)p;    p += sizeof(int) * NB_HIST * NEXP;
  int* base = (int*)p;  p += sizeof(int) * NB_HIST * NEXP;
  int* eid = (int*)p;   p += sizeof(int) * NTOK;
  int* tlist = (int*)p; p += sizeof(int) * NTOK;
  unsigned short* wfc_b = (unsigned short*)p; p += (size_t)NEXP * HID * DIM * 2;
  unsigned short* wpj_b = (unsigned short*)p; p += (size_t)NEXP * DIM * HID * 2;
  unsigned short* hbuf = (unsigned short*)p;  p += (size_t)NTOK * HID * 2;
  unsigned short* xb = (unsigned short*)p;    p += (size_t)NTOK * DIM * 2;

  k_router_cast<<<NB_ROUTER + NB_CAST, 256, 0, stream>>>(
      x, wr, eid, xb, wfc, wpj, wfc_b, wpj_b);
  k_hist<<<NB_HIST, 256, 0, stream>>>(eid, bc);
  k_scan<<<1, 256, 0, stream>>>(bc, offs, base);
  k_scatter<<<NB_HIST, 256, 0, stream>>>(eid, base, tlist);
  // fc: max tiles = 135 m-blocks * 4 n-blocks = 540 -> grid 544 (divisible by 8)
  k_gemm<1024, 512, 4, true><<<dim3(544), 256, 0, stream>>>(
      xb, nullptr, wfc_b, offs, tlist, hbuf, nullptr);
  // proj: max tiles = 135 * 8 = 1080 (divisible by 8)
  k_gemm<512, 1024, 8, false><<<dim3(1080), 256, 0, stream>>>(
      nullptr, hbuf, wpj_b, offs, tlist, nullptr, out);
}

// Round 9
// 107.382 us; speedup vs baseline: 1.0767x; 1.0767x over previous
//
#include <hip/hip_runtime.h>
#include <stdint.h>
#include <stddef.h>

#define DIM 1024
#define NEXP 8
#define HID 512
#define NTOK 16384  // 4 * 4096
#define NB_HIST 64
#define NB_ROUTER 1024  // router blocks (16 tokens each)
#define NB_CAST 512     // cast blocks appended after router blocks

typedef __attribute__((ext_vector_type(4))) float f32x4;
typedef __attribute__((ext_vector_type(8))) short short8;
typedef __attribute__((ext_vector_type(4))) unsigned short u16x4;
typedef __attribute__((ext_vector_type(8))) unsigned short u16x8;

__device__ __forceinline__ unsigned short f2b(float f) {
  unsigned int u = __float_as_uint(f);
  return (unsigned short)((u + 0x7FFFu + ((u >> 16) & 1u)) >> 16);  // RNE
}

__device__ __forceinline__ void gload_lds16(const unsigned short* g, unsigned short* l) {
  __builtin_amdgcn_global_load_lds((const __attribute__((address_space(1))) void*)g,
                                   (__attribute__((address_space(3))) void*)l, 16, 0, 0);
}

// Router (pure read, round-9: xb eliminated — top-1 routing reads each token row
// exactly once in fc, so pre-casting x had zero reuse; the store stream was the
// router's drag) + weight cast arm (blocks appended after router blocks).
__global__ __launch_bounds__(256) void k_router_cast(
    const float* __restrict__ x, const float* __restrict__ wr,
    int* __restrict__ eid,
    const float* __restrict__ wfc, const float* __restrict__ wpj,
    unsigned short* __restrict__ oa, unsigned short* __restrict__ ob) {
  int bid = blockIdx.x;
  if (bid < NB_ROUTER) {
    int w = threadIdx.x >> 6, lane = threadIdx.x & 63;
    int t0 = bid * 16 + w * 4;
    const float* xr = x + (size_t)t0 * DIM;
    float s[4][NEXP];
#pragma unroll
    for (int j = 0; j < 4; j++)
#pragma unroll
      for (int e = 0; e < NEXP; e++) s[j][e] = 0.f;
#pragma unroll
    for (int i = 0; i < 4; i++) {
      f32x4 xv[4];
#pragma unroll
      for (int j = 0; j < 4; j++) xv[j] = *(const f32x4*)(xr + j * DIM + lane * 4 + 256 * i);
#pragma unroll
      for (int e = 0; e < NEXP; e++) {
        f32x4 wv = *(const f32x4*)(wr + e * DIM + lane * 4 + 256 * i);
#pragma unroll
        for (int j = 0; j < 4; j++)
          s[j][e] += xv[j].x * wv.x + xv[j].y * wv.y + xv[j].z * wv.z + xv[j].w * wv.w;
      }
    }
#pragma unroll
    for (int j = 0; j < 4; j++)
#pragma unroll
      for (int e = 0; e < NEXP; e++) {
        float v = s[j][e];
#pragma unroll
        for (int off = 32; off > 0; off >>= 1) v += __shfl_xor(v, off);
        s[j][e] = v;
      }
    if (lane == 0) {
#pragma unroll
      for (int j = 0; j < 4; j++) {
        int be = 0;
        float bv = s[j][0];
#pragma unroll
        for (int e = 1; e < NEXP; e++) {
          if (s[j][e] > bv) { bv = s[j][e]; be = e; }
        }
        eid[t0 + j] = be;
      }
    }
  } else {
    const int n4 = NEXP * HID * DIM / 4;
    int stride = NB_CAST * 256;
    for (int i = (bid - NB_ROUTER) * 256 + (int)threadIdx.x; i < n4; i += stride) {
      f32x4 va = ((const f32x4*)wfc)[i];
      f32x4 vb = ((const f32x4*)wpj)[i];
      u16x4 ua, ub;
      ua.x = f2b(va.x); ua.y = f2b(va.y); ua.z = f2b(va.z); ua.w = f2b(va.w);
      ub.x = f2b(vb.x); ub.y = f2b(vb.y); ub.z = f2b(vb.z); ub.w = f2b(vb.w);
      ((u16x4*)oa)[i] = ua;
      ((u16x4*)ob)[i] = ub;
    }
  }
}

__global__ __launch_bounds__(256) void k_hist(const int* __restrict__ eid,
                                              int* __restrict__ bc) {
  __shared__ int h[NEXP];
  if (threadIdx.x < NEXP) h[threadIdx.x] = 0;
  __syncthreads();
  int tok = blockIdx.x * (NTOK / NB_HIST) + threadIdx.x;
  atomicAdd(&h[eid[tok]], 1);
  __syncthreads();
  if (threadIdx.x < NEXP) bc[blockIdx.x * NEXP + threadIdx.x] = h[threadIdx.x];
}

__global__ void k_scan(const int* __restrict__ bc, int* __restrict__ offs,
                       int* __restrict__ base) {
  __shared__ int cnt[NEXP];
  __shared__ int so[NEXP + 1];
  int t = threadIdx.x;
  if (t < NEXP) {
    int run = 0;
    for (int b = 0; b < NB_HIST; b++) {
      base[b * NEXP + t] = run;
      run += bc[b * NEXP + t];
    }
    cnt[t] = run;
  }
  __syncthreads();
  if (t == 0) {
    int a = 0;
    for (int e = 0; e < NEXP; e++) { so[e] = a; a += cnt[e]; }
    so[NEXP] = a;
  }
  __syncthreads();
  if (t < NEXP + 1) offs[t] = so[t];
  for (int i = t; i < NB_HIST * NEXP; i += blockDim.x) base[i] += so[i % NEXP];
}

__global__ __launch_bounds__(256) void k_scatter(const int* __restrict__ eid,
                                                 const int* __restrict__ base,
                                                 int* __restrict__ tlist) {
  __shared__ int cur[NEXP];
  if (threadIdx.x < NEXP) cur[threadIdx.x] = base[blockIdx.x * NEXP + threadIdx.x];
  __syncthreads();
  int tok = blockIdx.x * (NTOK / NB_HIST) + threadIdx.x;
  int e = eid[tok];
  int pos = atomicAdd(&cur[e], 1);
  tlist[pos] = tok;
}

// Common tile mapping: XCD-chunked 1-D grid, (expert, m-block, n-block), n fastest.
__device__ __forceinline__ bool tile_map(const int* offs, int NB, int& e, int& mb,
                                         int& nb) {
  int l = ((int)blockIdx.x & 7) * ((int)gridDim.x >> 3) + ((int)blockIdx.x >> 3);
  e = -1; mb = 0; nb = 0;
  int acc2 = 0;
#pragma unroll
  for (int i = 0; i < NEXP; i++) {
    int mi = offs[i + 1] - offs[i];
    int tb = ((mi + 127) >> 7) * NB;
    if (e < 0 && l < acc2 + tb) {
      int r = l - acc2;
      e = i; mb = r / NB; nb = r % NB;
    }
    acc2 += tb;
  }
  return e >= 0;
}

// fc GEMM: A = fp32 x (gathered, REG-STAGED with fp32->bf16 convert, T14 split:
// issue post-barrier / ds_write pre-barrier-next-iter), B = bf16 wfc via
// global_load_lds depth-2. Ring-3 LDS 48 KB. Swizzle (round-9 fix): LDS chunk c
// of row r holds global chunk c^((r>>1)&3) — rows alias banks only at +8 (2-way,
// free); the old (r&3) form was a 4-way read conflict.
// vmcnt ledger (per-iter issue order [A x4, B x2]): steady wait = vmcnt(2).
__global__ __launch_bounds__(256) void k_gemm_fc(
    const float* __restrict__ x, const unsigned short* __restrict__ wb,
    const int* __restrict__ offs, const int* __restrict__ tlist,
    unsigned short* __restrict__ hout) {
  constexpr int KDIM = DIM, NDIM = HID;
  int e, mb, nb;
  if (!tile_map(offs, 4, e, mb, nb)) return;
  int off = offs[e], me = offs[e + 1] - off, m0 = mb * 128, n0 = nb * 128;

  __shared__ unsigned short As[3][128 * 32];
  __shared__ unsigned short Bs[3][128 * 32];

  int t = threadIdx.x, lane = t & 63, w = t >> 6;
  int wm = w >> 1, wn = w & 1;

  int kb = (lane & 3) ^ ((lane >> 3) & 3);  // global chunk for this lane's LDS slot

  const unsigned short* bsrc[2];
  const float* af32[2];
#pragma unroll
  for (int i = 0; i < 2; i++) {
    int r = i * 64 + w * 16 + (lane >> 2);
    bsrc[i] = wb + ((size_t)e * NDIM + n0 + r) * (size_t)KDIM + kb * 8;
    int gm = m0 + r;
    if (gm > me - 1) gm = me - 1;
    af32[i] = x + (size_t)tlist[off + gm] * DIM + kb * 8;
  }
  int awoff0 = (w * 16) * 32 + lane * 8;        // part 0 LDS elem offset
  int awoff1 = (64 + w * 16) * 32 + lane * 8;   // part 1

  f32x4 acc[4][4] = {};
  constexpr int NT = KDIM / 32;  // 32

  unsigned short* a0 = &As[0][0]; unsigned short* b0 = &Bs[0][0];
  unsigned short* a1 = &As[1][0]; unsigned short* b1 = &Bs[1][0];
  unsigned short* a2 = &As[2][0]; unsigned short* b2 = &Bs[2][0];

  f32x4 r00, r01, r10, r11;  // in-flight A regs (one tile)

#define ISSUE_A(kt_)                                              \
  do {                                                            \
    r00 = *(const f32x4*)(af32[0] + (kt_) * 32);                  \
    r01 = *(const f32x4*)(af32[0] + (kt_) * 32 + 4);              \
    r10 = *(const f32x4*)(af32[1] + (kt_) * 32);                  \
    r11 = *(const f32x4*)(af32[1] + (kt_) * 32 + 4);              \
  } while (0)
#define ISSUE_B(kt_, db_)                                         \
  do {                                                            \
    gload_lds16(bsrc[0] + (kt_) * 32, (db_) + (w * 16) * 32);     \
    gload_lds16(bsrc[1] + (kt_) * 32, (db_) + (64 + w * 16) * 32);\
  } while (0)
#define WRITE_A(da_)                                              \
  do {                                                            \
    u16x8 c0, c1;                                                 \
    c0[0] = f2b(r00.x); c0[1] = f2b(r00.y); c0[2] = f2b(r00.z); c0[3] = f2b(r00.w); \
    c0[4] = f2b(r01.x); c0[5] = f2b(r01.y); c0[6] = f2b(r01.z); c0[7] = f2b(r01.w); \
    c1[0] = f2b(r10.x); c1[1] = f2b(r10.y); c1[2] = f2b(r10.z); c1[3] = f2b(r10.w); \
    c1[4] = f2b(r11.x); c1[5] = f2b(r11.y); c1[6] = f2b(r11.z); c1[7] = f2b(r11.w); \
    *(u16x8*)&(da_)[awoff0] = c0;                                 \
    *(u16x8*)&(da_)[awoff1] = c1;                                 \
  } while (0)

  // prologue: A(0) x4, B(0) x2, B(1) x2 in flight
  ISSUE_A(0);
  ISSUE_B(0, b0);
  ISSUE_B(1, b1);

  for (int kt = 0; kt < NT; kt++) {
    if (kt == NT - 1) {
      asm volatile("s_waitcnt vmcnt(0)" ::: "memory");
    } else {
      asm volatile("s_waitcnt vmcnt(2)" ::: "memory");  // A(kt)+B(kt) done
    }
    __builtin_amdgcn_sched_barrier(0);
    WRITE_A(a0);  // tile kt -> slot kt%3
    asm volatile("s_waitcnt lgkmcnt(0)" ::: "memory");
    __builtin_amdgcn_sched_barrier(0);
    __builtin_amdgcn_s_barrier();
    if (kt + 1 < NT) ISSUE_A(kt + 1);
    if (kt + 2 < NT) ISSUE_B(kt + 2, b2);

    short8 af[4], bf[4];
#pragma unroll
    for (int i = 0; i < 4; i++) {
      int ra = wm * 64 + i * 16 + (lane & 15);
      int ca = (lane >> 4) ^ ((ra >> 1) & 3);
      af[i] = *(const short8*)&a0[ra * 32 + ca * 8];
      int rbb = wn * 64 + i * 16 + (lane & 15);
      int cb = (lane >> 4) ^ ((rbb >> 1) & 3);
      bf[i] = *(const short8*)&b0[rbb * 32 + cb * 8];
    }
    __builtin_amdgcn_s_setprio(1);
#pragma unroll
    for (int mi = 0; mi < 4; mi++)
#pragma unroll
      for (int ni = 0; ni < 4; ni++)
        acc[mi][ni] =
            __builtin_amdgcn_mfma_f32_16x16x32_bf16(af[mi], bf[ni], acc[mi][ni], 0, 0, 0);
    __builtin_amdgcn_s_setprio(0);

    unsigned short* ta = a0; a0 = a1; a1 = a2; a2 = ta;
    unsigned short* tb = b0; b0 = b1; b1 = b2; b2 = tb;
  }
#undef ISSUE_A
#undef ISSUE_B
#undef WRITE_A

  int rb = (lane >> 4) * 4, cb = lane & 15;
#pragma unroll
  for (int mi = 0; mi < 4; mi++) {
#pragma unroll
    for (int j = 0; j < 4; j++) {
      int ml = wm * 64 + mi * 16 + rb + j;
      if (m0 + ml < me) {
#pragma unroll
        for (int ni = 0; ni < 4; ni++) {
          int col = n0 + wn * 64 + ni * 16 + cb;
          float v = acc[mi][ni][j];
          v = (v >= 0.f) ? v * v : 0.25f * v * v;  // leaky(0.5) then square
          hout[(size_t)(off + m0 + ml) * HID + col] = f2b(v);
        }
      }
    }
  }
}

// proj GEMM: both operands bf16 via global_load_lds, ring-3 depth-2 (round-6
// schedule) with the round-9 swizzle fix.
__global__ __launch_bounds__(256) void k_gemm_pj(
    const unsigned short* __restrict__ hin, const unsigned short* __restrict__ wb,
    const int* __restrict__ offs, const int* __restrict__ tlist,
    float* __restrict__ out) {
  constexpr int KDIM = HID, NDIM = DIM;
  int e, mb, nb;
  if (!tile_map(offs, 8, e, mb, nb)) return;
  int off = offs[e], me = offs[e + 1] - off, m0 = mb * 128, n0 = nb * 128;

  __shared__ unsigned short lds[3][2][128 * 32];

  int t = threadIdx.x, lane = t & 63, w = t >> 6;
  int wm = w >> 1, wn = w & 1;

  int kb = (lane & 3) ^ ((lane >> 3) & 3);

  const unsigned short* asrc[2];
  const unsigned short* bsrc[2];
#pragma unroll
  for (int i = 0; i < 2; i++) {
    int r = i * 64 + w * 16 + (lane >> 2);
    int gm = m0 + r;
    if (gm > me - 1) gm = me - 1;
    asrc[i] = hin + (size_t)(off + gm) * KDIM + kb * 8;
    bsrc[i] = wb + ((size_t)e * NDIM + n0 + r) * (size_t)KDIM + kb * 8;
  }

  f32x4 acc[4][4] = {};
  constexpr int NT = KDIM / 32;  // 16

  unsigned short* b0a = &lds[0][0][0]; unsigned short* b0b = &lds[0][1][0];
  unsigned short* b1a = &lds[1][0][0]; unsigned short* b1b = &lds[1][1][0];
  unsigned short* b2a = &lds[2][0][0]; unsigned short* b2b = &lds[2][1][0];

#define STAGE(kt_, da_, db_)                                       \
  do {                                                             \
    gload_lds16(asrc[0] + (kt_) * 32, (da_) + (w * 16) * 32);      \
    gload_lds16(asrc[1] + (kt_) * 32, (da_) + (64 + w * 16) * 32); \
    gload_lds16(bsrc[0] + (kt_) * 32, (db_) + (w * 16) * 32);      \
    gload_lds16(bsrc[1] + (kt_) * 32, (db_) + (64 + w * 16) * 32); \
  } while (0)

  STAGE(0, b0a, b0b);
  STAGE(1, b1a, b1b);

  for (int kt = 0; kt < NT; kt++) {
    if (kt < NT - 1) {
      asm volatile("s_waitcnt vmcnt(4)" ::: "memory");
    } else {
      asm volatile("s_waitcnt vmcnt(0)" ::: "memory");
    }
    __builtin_amdgcn_s_barrier();

    if (kt + 2 < NT) STAGE(kt + 2, b2a, b2b);

    short8 af[4], bf[4];
#pragma unroll
    for (int i = 0; i < 4; i++) {
      int ra = wm * 64 + i * 16 + (lane & 15);
      int ca = (lane >> 4) ^ ((ra >> 1) & 3);
      af[i] = *(const short8*)&b0a[ra * 32 + ca * 8];
      int rbb = wn * 64 + i * 16 + (lane & 15);
      int cb = (lane >> 4) ^ ((rbb >> 1) & 3);
      bf[i] = *(const short8*)&b0b[rbb * 32 + cb * 8];
    }
    __builtin_amdgcn_s_setprio(1);
#pragma unroll
    for (int mi = 0; mi < 4; mi++)
#pragma unroll
      for (int ni = 0; ni < 4; ni++)
        acc[mi][ni] =
            __builtin_amdgcn_mfma_f32_16x16x32_bf16(af[mi], bf[ni], acc[mi][ni], 0, 0, 0);
    __builtin_amdgcn_s_setprio(0);

    unsigned short* ta = b0a; b0a = b1a; b1a = b2a; b2a = ta;
    unsigned short* tb = b0b; b0b = b1b; b1b = b2b; b2b = tb;
  }
#undef STAGE

  int rb = (lane >> 4) * 4, cb = lane & 15;
#pragma unroll
  for (int mi = 0; mi < 4; mi++) {
#pragma unroll
    for (int j = 0; j < 4; j++) {
      int ml = wm * 64 + mi * 16 + rb + j;
      if (m0 + ml < me) {
        int tok = tlist[off + m0 + ml];
#pragma unroll
        for (int ni = 0; ni < 4; ni++) {
          int col = n0 + wn * 64 + ni * 16 + cb;
          out[(size_t)tok * DIM + col] = acc[mi][ni][j];
        }
      }
    }
  }
}

extern "C" void kernel_launch(void* const* d_in, const int* in_sizes, int n_in,
                              void* d_out, int out_size, void* d_ws, size_t ws_size,
                              hipStream_t stream) {
  const float* x = (const float*)d_in[0];
  const float* wr = (const float*)d_in[1];
  const float* wfc = (const float*)d_in[2];
  const float* wpj = (const float*)d_in[3];
  float* out = (float*)d_out;

  uintptr_t p = (uintptr_t)d_ws;
  int* offs = (int*)p;  p += 256;
  int* bc = (int*)p;    p += sizeof(int) * NB_HIST * NEXP;
  int* base = (int*)p;  p += sizeof(int) * NB_HIST * NEXP;
  int* eid = (int*)p;   p += sizeof(int) * NTOK;
  int* tlist = (int*)p; p += sizeof(int) * NTOK;
  unsigned short* wfc_b = (unsigned short*)p; p += (size_t)NEXP * HID * DIM * 2;
  unsigned short* wpj_b = (unsigned short*)p; p += (size_t)NEXP * DIM * HID * 2;
  unsigned short* hbuf = (unsigned short*)p;  p += (size_t)NTOK * HID * 2;

  k_router_cast<<<NB_ROUTER + NB_CAST, 256, 0, stream>>>(
      x, wr, eid, wfc, wpj, wfc_b, wpj_b);
  k_hist<<<NB_HIST, 256, 0, stream>>>(eid, bc);
  k_scan<<<1, 256, 0, stream>>>(bc, offs, base);
  k_scatter<<<NB_HIST, 256, 0, stream>>>(eid, base, tlist);
  k_gemm_fc<<<dim3(544), 256, 0, stream>>>(x, wfc_b, offs, tlist, hbuf);
  k_gemm_pj<<<dim3(1080), 256, 0, stream>>>(hbuf, wpj_b, offs, tlist, out);
}